// Round 2
// baseline (607.341 us; speedup 1.0000x reference)
//
#include <hip/hip_runtime.h>
#include <math.h>

// VectorQuantizer — bitwise-emulate the numpy fp32 reference:
//   d[n,k] = fl32( fl32(x2[n] + c2[k]) - fl32(2 * dot[n,k]) ),  idx = first argmin
// x2/c2 use numpy's pairwise-summation order (8-accumulator, n=64 block).
// dot is computed exactly in fp64 and rounded once to fp32 (stand-in for
// numpy's fp32 einsum accumulation; differs only ~1e-8 which is ~0.3% of the
// d-grid ulp). All bit-critical fp32 ops use __f*_rn to forbid contraction.

#define N_CODES   512
#define CODE_DIM  64
#define BATCH     16
#define HH        64
#define WW        64
#define CH_STRIDE (HH * WW)                 // 4096 floats between channels
#define B_STRIDE  (CODE_DIM * CH_STRIDE)    // 262144 floats between batches
#define N_WAVES   (BATCH * HH)              // 1024 waves, one (b,h) pair each

// numpy pairwise_sum for n=64, unit stride (loops.c.src):
//   r[j] = a[j]; for (i=8; i<64; i+=8) r[j] += a[i+j];
//   res = ((r0+r1)+(r2+r3)) + ((r4+r5)+(r6+r7));
__device__ __forceinline__ float np_pairwise_sum64(const float* a) {
    float r[8];
#pragma unroll
    for (int j = 0; j < 8; ++j) r[j] = a[j];
#pragma unroll
    for (int i = 8; i < 64; i += 8) {
#pragma unroll
        for (int j = 0; j < 8; ++j) r[j] = __fadd_rn(r[j], a[i + j]);
    }
    return __fadd_rn(__fadd_rn(__fadd_rn(r[0], r[1]), __fadd_rn(r[2], r[3])),
                     __fadd_rn(__fadd_rn(r[4], r[5]), __fadd_rn(r[6], r[7])));
}

// Setup: c2[k] = np.sum(cb[k]*cb[k]) in numpy order; cb64 = fp64 copy of cb.
__global__ void vq_setup_kernel(const float* __restrict__ cb,
                                float* __restrict__ c2,
                                double* __restrict__ cb64, int do64) {
    const int t = blockIdx.x * blockDim.x + threadIdx.x;
    const int nthreads = gridDim.x * blockDim.x;
    if (do64) {
        for (int i = t; i < N_CODES * CODE_DIM; i += nthreads)
            cb64[i] = (double)cb[i];
    }
    if (t < N_CODES) {
        const float* row = cb + t * CODE_DIM;
        float sq[CODE_DIM];
#pragma unroll
        for (int j = 0; j < CODE_DIM; ++j) sq[j] = __fmul_rn(row[j], row[j]);
        c2[t] = np_pairwise_sum64(sq);
    }
}

// One wave per (b,h): lane = w -> coalesced 256B channel loads.
// Codebook accesses are wave-uniform -> scalar loads.
template <bool HAS_CB64>
__global__ void vq_main_kernel(const float* __restrict__ in,
                               const float* __restrict__ cb,
                               const float* __restrict__ c2,
                               const double* __restrict__ cb64,
                               float* __restrict__ out) {
    const int lane = threadIdx.x & 63;
    const int gw   = blockIdx.x * (blockDim.x >> 6) + (threadIdx.x >> 6); // 0..1023
    const int b    = gw >> 6;
    const int h    = gw & 63;

    // Load this lane's row vector x[0..63] (stride 4096 floats; coalesced across lanes).
    const float* xin = in + (size_t)b * B_STRIDE + (size_t)h * WW + lane;
    float x[CODE_DIM];
#pragma unroll
    for (int c = 0; c < CODE_DIM; ++c) x[c] = xin[(size_t)c * CH_STRIDE];

    // x2 = np.sum(x*x) in numpy pairwise order (squares rounded separately).
    float sq[CODE_DIM];
#pragma unroll
    for (int j = 0; j < CODE_DIM; ++j) sq[j] = __fmul_rn(x[j], x[j]);
    const float x2 = np_pairwise_sum64(sq);

    // Keep x in fp64 for the exact dot.
    double x64[CODE_DIM];
#pragma unroll
    for (int j = 0; j < CODE_DIM; ++j) x64[j] = (double)x[j];

    float best = INFINITY;
    int   bi   = 0;

    for (int k = 0; k < N_CODES; ++k) {
        double a0 = 0.0, a1 = 0.0, a2 = 0.0, a3 = 0.0;
        if (HAS_CB64) {
            const double* crow = cb64 + (size_t)k * CODE_DIM;
#pragma unroll
            for (int j = 0; j < CODE_DIM; j += 4) {
                a0 = fma(crow[j + 0], x64[j + 0], a0);
                a1 = fma(crow[j + 1], x64[j + 1], a1);
                a2 = fma(crow[j + 2], x64[j + 2], a2);
                a3 = fma(crow[j + 3], x64[j + 3], a3);
            }
        } else {
            const float* crow = cb + (size_t)k * CODE_DIM;
#pragma unroll
            for (int j = 0; j < CODE_DIM; j += 4) {
                a0 = fma((double)crow[j + 0], x64[j + 0], a0);
                a1 = fma((double)crow[j + 1], x64[j + 1], a1);
                a2 = fma((double)crow[j + 2], x64[j + 2], a2);
                a3 = fma((double)crow[j + 3], x64[j + 3], a3);
            }
        }
        const double dot = (a0 + a1) + (a2 + a3);
        const float  ein = (float)dot;                        // fl32(exact dot)
        const float  tmp = __fadd_rn(x2, c2[k]);              // fl32(x2 + c2)
        const float  dk  = __fsub_rn(tmp, __fmul_rn(2.0f, ein)); // fl32(tmp - 2*ein)
        if (dk < best) { best = dk; bi = k; }                 // first-min wins (np.argmin)
    }

    // Write rows n0..n0+63: broadcast lane r's index; coalesced 256B row store.
    const size_t n0 = (size_t)gw * 64;
    for (int r = 0; r < 64; ++r) {
        int idx_r = __shfl(bi, r, 64);
        out[(n0 + r) * CODE_DIM + lane] = cb[(size_t)idx_r * CODE_DIM + lane];
    }
}

extern "C" void kernel_launch(void* const* d_in, const int* in_sizes, int n_in,
                              void* d_out, int out_size, void* d_ws, size_t ws_size,
                              hipStream_t stream) {
    const float* in  = (const float*)d_in[0];   // (16,64,64,64) fp32
    const float* cb  = (const float*)d_in[1];   // (512,64) fp32
    float*       out = (float*)d_out;           // (16,64,64,64) fp32

    // ws layout: [0,2048) c2 (512 f32) ; [2048, 2048+256K) cb64 (512*64 f64)
    float*  c2   = (float*)d_ws;
    double* cb64 = (double*)((char*)d_ws + 2048);
    const bool has64 = ws_size >= (size_t)(2048 + N_CODES * CODE_DIM * sizeof(double));

    vq_setup_kernel<<<dim3(32), dim3(256), 0, stream>>>(cb, c2, cb64, has64 ? 1 : 0);

    if (has64)
        vq_main_kernel<true ><<<dim3(N_WAVES / 4), dim3(256), 0, stream>>>(in, cb, c2, cb64, out);
    else
        vq_main_kernel<false><<<dim3(N_WAVES / 4), dim3(256), 0, stream>>>(in, cb, c2, cb64, out);
}

// Round 3
// 373.361 us; speedup vs baseline: 1.6267x; 1.6267x over previous
//
#include <hip/hip_runtime.h>
#include <math.h>

// VectorQuantizer — bit-exact emulation of the numpy fp32 reference (proven in R2):
//   d[n,k] = fl32( fl32(x2[n]+c2[k]) - fl32(2 * fl32(exact_dot)) ), idx = first argmin
// R2 computed the exact dk for all 512 codes in fp64 and passed, but spilled
// x[]/x64[] to scratch (VGPR=64, 31GB scratch traffic, 541us). R3: fp32 fast scan
// (registers only) + per-lane candidate buffer + fp64-exact re-resolution of the
// few candidates. Guarantees the same argmin as R2's exact scan.

#define N_CODES   512
#define CODE_DIM  64
#define BATCH     16
#define HH        64
#define WW        64
#define CH_STRIDE (HH * WW)                 // 4096 floats between channels
#define B_STRIDE  (CODE_DIM * CH_STRIDE)    // 262144 floats between batches
#define N_WAVES   (BATCH * HH)              // 1024 waves, one (b,h) pair each
#define CAP       24                        // candidate buffer capacity per lane

// numpy pairwise_sum for n=64, unit stride (loops.c.src):
__device__ __forceinline__ float np_pairwise_sum64(const float* a) {
    float r[8];
#pragma unroll
    for (int j = 0; j < 8; ++j) r[j] = a[j];
#pragma unroll
    for (int i = 8; i < 64; i += 8) {
#pragma unroll
        for (int j = 0; j < 8; ++j) r[j] = __fadd_rn(r[j], a[i + j]);
    }
    return __fadd_rn(__fadd_rn(__fadd_rn(r[0], r[1]), __fadd_rn(r[2], r[3])),
                     __fadd_rn(__fadd_rn(r[4], r[5]), __fadd_rn(r[6], r[7])));
}

__global__ void vq_setup_kernel(const float* __restrict__ cb, float* __restrict__ c2) {
    const int k = blockIdx.x * blockDim.x + threadIdx.x;
    if (k < N_CODES) {
        const float* row = cb + k * CODE_DIM;
        float sq[CODE_DIM];
#pragma unroll
        for (int j = 0; j < CODE_DIM; ++j) sq[j] = __fmul_rn(row[j], row[j]);
        c2[k] = np_pairwise_sum64(sq);
    }
}

// Exact dk — identical arithmetic to the R2 kernel that passed (fp64 4-chain dot,
// rounded once to fp32, then the numpy-order fp32 formula).
__device__ __forceinline__ float exact_dk(const float* __restrict__ cb,
                                          const float* __restrict__ c2,
                                          const float* x, float x2, int k) {
    const float* crow = cb + (size_t)k * CODE_DIM;
    double a0 = 0.0, a1 = 0.0, a2 = 0.0, a3 = 0.0;
#pragma unroll
    for (int j = 0; j < CODE_DIM; j += 4) {
        a0 = fma((double)crow[j + 0], (double)x[j + 0], a0);
        a1 = fma((double)crow[j + 1], (double)x[j + 1], a1);
        a2 = fma((double)crow[j + 2], (double)x[j + 2], a2);
        a3 = fma((double)crow[j + 3], (double)x[j + 3], a3);
    }
    const double dot = (a0 + a1) + (a2 + a3);
    const float  ein = (float)dot;
    const float  tmp = __fadd_rn(x2, c2[k]);
    return __fsub_rn(tmp, __fmul_rn(2.0f, ein));
}

// One wave per (b,h): lane = w -> coalesced 256B channel loads. Codebook reads in
// the hot loop are wave-uniform -> scalar loads; VALU stays on fp32 FMAs.
__global__ __launch_bounds__(256, 1)
void vq_main_kernel(const float* __restrict__ in,
                    const float* __restrict__ cb,
                    const float* __restrict__ c2,
                    float* __restrict__ out) {
    __shared__ float s_cdk[256][CAP];   // per-thread candidate dk_fast
    __shared__ int   s_cki[256][CAP];   // per-thread candidate k (ascending)

    const int tid  = threadIdx.x;
    const int lane = tid & 63;
    const int gw   = blockIdx.x * 4 + (tid >> 6);   // 0..1023
    const int b    = gw >> 6;
    const int h    = gw & 63;

    // x[0..63] in VGPRs (stride-4096 loads, coalesced across lanes).
    const float* xin = in + (size_t)b * B_STRIDE + (size_t)h * WW + lane;
    float x[CODE_DIM];
#pragma unroll
    for (int c = 0; c < CODE_DIM; ++c) x[c] = xin[(size_t)c * CH_STRIDE];

    // x2 = np.sum(x*x), numpy pairwise order (squares rounded separately).
    float sq[CODE_DIM];
#pragma unroll
    for (int j = 0; j < CODE_DIM; ++j) sq[j] = __fmul_rn(x[j], x[j]);
    const float x2 = np_pairwise_sum64(sq);

    // --- Pass 1: fp32 fast scan + candidate capture -------------------------
    // |dk_fast - dk_exact| <= E = 2*e_dot + g, e_dot <= ~1e-6, g = ulp(dk).
    // Capture rule: any k with dk_fast <= best + thr, thr = 4.5*ulp(best)+8e-6
    // >= 2E (binade-safe) => exact argmin is always in the buffer.
    float best = INFINITY;
    float cut  = INFINITY;   // best + thr
    int   count = 0, overflow = 0;

#pragma unroll 2
    for (int k = 0; k < N_CODES; ++k) {
        const float* crow = cb + (size_t)k * CODE_DIM;
        float a0 = 0.f, a1 = 0.f, a2 = 0.f, a3 = 0.f;
#pragma unroll
        for (int j = 0; j < CODE_DIM; j += 4) {
            a0 = fmaf(x[j + 0], crow[j + 0], a0);
            a1 = fmaf(x[j + 1], crow[j + 1], a1);
            a2 = fmaf(x[j + 2], crow[j + 2], a2);
            a3 = fmaf(x[j + 3], crow[j + 3], a3);
        }
        const float dot = __fadd_rn(__fadd_rn(a0, a1), __fadd_rn(a2, a3));
        const float dk  = __fsub_rn(__fadd_rn(x2, c2[k]), __fmul_rn(2.0f, dot));

        const bool ins = (dk <= cut);
        if (dk < best) {
            best = dk;
            // g = 2^exponent(best) * 2^-23 ; thr = 4.5*g + 8e-6
            const float g = __uint_as_float(__float_as_uint(best) & 0xFF800000u)
                            * 1.1920929e-7f;
            cut = __fadd_rn(best, __fmaf_rn(4.5f, g, 8e-6f));
        }
        if (ins) {
            if (count == CAP) {            // compact: drop stale entries
                int nc = 0;
#pragma unroll 1
                for (int i = 0; i < CAP; ++i) {
                    const float d  = s_cdk[tid][i];
                    const int   kk = s_cki[tid][i];
                    if (d <= cut) { s_cdk[tid][nc] = d; s_cki[tid][nc] = kk; ++nc; }
                }
                count = nc;
            }
            if (count < CAP) {
                s_cdk[tid][count] = dk;
                s_cki[tid][count] = k;
                ++count;
            } else {
                overflow = 1;
            }
        }
    }

    // --- Pass 2: exact re-resolution of candidates (R2 arithmetic) ----------
    float ex_best = INFINITY;
    int   bi = 0;
#pragma unroll 1
    for (int i = 0; i < count; ++i) {
        const int   k  = s_cki[tid][i];
        const float dk = exact_dk(cb, c2, x, x2, k);
        if (dk < ex_best) { ex_best = dk; bi = k; }   // ascending k => first-min
    }
    if (__builtin_amdgcn_ballot_w64(overflow != 0)) {  // ~never: full exact rescan
        if (overflow) {
            ex_best = INFINITY; bi = 0;
#pragma unroll 1
            for (int k = 0; k < N_CODES; ++k) {
                const float dk = exact_dk(cb, c2, x, x2, k);
                if (dk < ex_best) { ex_best = dk; bi = k; }
            }
        }
    }

    // --- Output: rows n0..n0+63, coalesced 256B row loads/stores ------------
    const size_t n0 = (size_t)gw * 64;
    for (int r = 0; r < 64; ++r) {
        const int idx_r = __shfl(bi, r, 64);
        out[(n0 + r) * CODE_DIM + lane] = cb[(size_t)idx_r * CODE_DIM + lane];
    }
}

extern "C" void kernel_launch(void* const* d_in, const int* in_sizes, int n_in,
                              void* d_out, int out_size, void* d_ws, size_t ws_size,
                              hipStream_t stream) {
    const float* in  = (const float*)d_in[0];   // (16,64,64,64) fp32
    const float* cb  = (const float*)d_in[1];   // (512,64) fp32
    float*       out = (float*)d_out;           // (16,64,64,64) fp32
    float*       c2  = (float*)d_ws;            // 512 floats scratch

    vq_setup_kernel<<<dim3(2), dim3(256), 0, stream>>>(cb, c2);
    vq_main_kernel<<<dim3(N_WAVES / 4), dim3(256), 0, stream>>>(in, cb, c2, out);
}